// Round 7
// baseline (567.892 us; speedup 1.0000x reference)
//
#include <hip/hip_runtime.h>

typedef __attribute__((ext_vector_type(8))) short bf16x8;
typedef __attribute__((ext_vector_type(4))) float f32x4;
typedef __attribute__((ext_vector_type(8))) unsigned short u16x8;

#define H_Q   16
#define NH    18            // 16 q heads + 1 k + 1 v
#define SEQ   2048
#define BATCH 2
#define HID   2048
#define NQKV  2304          // NH*128
#define QK_SCALE 0.08838834764831845f  // 1/sqrt(128)

__device__ __forceinline__ float bf2f(unsigned short u){
  union { unsigned int u; float f; } x; x.u = ((unsigned int)u) << 16; return x.f;
}
__device__ __forceinline__ unsigned short f2bf(float f){
  union { float f; unsigned int u; } x; x.f = f;
  unsigned int r = x.u + 0x7fffu + ((x.u >> 16) & 1u);
  return (unsigned short)(r >> 16);
}

// ---------------------------------------------------------------- f32 -> bf16 convert
__global__ __launch_bounds__(256) void convert_bf16(const float* __restrict__ src,
                                                    unsigned short* __restrict__ dst){
  const size_t i0 = ((size_t)blockIdx.x * 256 + threadIdx.x) * 16;
  f32x4 a = *(const f32x4*)(src + i0);
  f32x4 b = *(const f32x4*)(src + i0 + 4);
  f32x4 c = *(const f32x4*)(src + i0 + 8);
  f32x4 d = *(const f32x4*)(src + i0 + 12);
  u16x8 lo, hi;
#pragma unroll
  for (int j = 0; j < 4; ++j){
    lo[j] = f2bf(a[j]); lo[4+j] = f2bf(b[j]);
    hi[j] = f2bf(c[j]); hi[4+j] = f2bf(d[j]);
  }
  *(u16x8*)(dst + i0)     = lo;
  *(u16x8*)(dst + i0 + 8) = hi;
}

// ---------------------------------------------------------------- transpose + convert
// W: K x N (row-major, f32) -> WT: N x K (row-major, bf16). 64x64 tiles.
__global__ __launch_bounds__(256) void transpose_f2b(const float* __restrict__ W,
                                                     unsigned short* __restrict__ WT,
                                                     int K, int N){
  __shared__ float tile[64][72];
  const int t = threadIdx.x;
  const int nt = blockIdx.x * 64, kt = blockIdx.y * 64;
#pragma unroll
  for (int p = 0; p < 2; ++p){
    int slot = p*256 + t, r = slot >> 3, c = (slot & 7) * 8;
    *(f32x4*)&tile[r][c]     = *(const f32x4*)(W + (size_t)(kt + r)*N + nt + c);
    *(f32x4*)&tile[r][c + 4] = *(const f32x4*)(W + (size_t)(kt + r)*N + nt + c + 4);
  }
  __syncthreads();
#pragma unroll
  for (int p = 0; p < 2; ++p){
    int slot = p*256 + t, r = slot >> 3, c = (slot & 7) * 8;
    u16x8 v;
#pragma unroll
    for (int j = 0; j < 8; ++j) v[j] = f2bf(tile[c + j][r]);
    *(u16x8*)(WT + (size_t)(nt + r)*K + kt + c) = v;
  }
}

// ---------------------------------------------------------------- GEMM (B^T input)
// C(MxN) = A(MxK, rm) * Bt(NxK, rm)^T.  128x128 tile, BK=32, 4 waves (2x2 of 64x64).
// F32OUT: C is float*, else bf16 (unsigned short*).
template<bool F32OUT>
__global__ __launch_bounds__(256, 2) void gemm_bt(const unsigned short* __restrict__ A,
                                                  const unsigned short* __restrict__ Bt,
                                                  void* __restrict__ Cv,
                                                  int M, int N, int K){
  __shared__ unsigned short lds[2][2][128*32];
  const int tid  = threadIdx.x;
  const int wave = tid >> 6, lane = tid & 63;
  const int row0 = blockIdx.x * 128, col0 = blockIdx.y * 128;
  const int wr = (wave >> 1) * 64, wc = (wave & 1) * 64;
  const int lm = lane & 15, lk = (lane >> 4) * 8;
  f32x4 acc[4][4] = {};

  auto stage = [&](int buf, int kt){
#pragma unroll
    for (int i = 0; i < 2; ++i){
      int slot = i*256 + tid;
      int r = slot >> 2, kc = (slot & 3) * 8;
      const unsigned short* ga = A  + (size_t)(row0 + r)*K + kt*32 + kc;
      const unsigned short* gb = Bt + (size_t)(col0 + r)*K + kt*32 + kc;
      unsigned short* la = &lds[buf][0][(i*256 + (wave << 6)) * 8];
      unsigned short* lb = &lds[buf][1][(i*256 + (wave << 6)) * 8];
      __builtin_amdgcn_global_load_lds((const __attribute__((address_space(1))) void*)ga,
                                       (__attribute__((address_space(3))) void*)la, 16, 0, 0);
      __builtin_amdgcn_global_load_lds((const __attribute__((address_space(1))) void*)gb,
                                       (__attribute__((address_space(3))) void*)lb, 16, 0, 0);
    }
  };

  stage(0, 0);
  const int KT = K >> 5;
  int buf = 0;
  for (int kt = 0; kt < KT; ++kt){
    __syncthreads();                       // drains vmcnt: staged tile ready, prev reads done
    if (kt + 1 < KT) stage(buf ^ 1, kt + 1);
    const unsigned short* la = lds[buf][0];
    const unsigned short* lb = lds[buf][1];
    bf16x8 af[4], bfr[4];
#pragma unroll
    for (int i = 0; i < 4; ++i) af[i]  = *(const bf16x8*)&la[(wr + i*16 + lm)*32 + lk];
#pragma unroll
    for (int j = 0; j < 4; ++j) bfr[j] = *(const bf16x8*)&lb[(wc + j*16 + lm)*32 + lk];
#pragma unroll
    for (int i = 0; i < 4; ++i)
#pragma unroll
      for (int j = 0; j < 4; ++j)
        acc[i][j] = __builtin_amdgcn_mfma_f32_16x16x32_bf16(af[i], bfr[j], acc[i][j], 0, 0, 0);
    buf ^= 1;
  }

#pragma unroll
  for (int i = 0; i < 4; ++i){
    int row = row0 + wr + i*16 + (lane >> 4) * 4;
#pragma unroll
    for (int j = 0; j < 4; ++j){
      int col = col0 + wc + j*16 + lm;
#pragma unroll
      for (int r = 0; r < 4; ++r){
        if (F32OUT) ((float*)Cv)[(size_t)(row + r)*N + col] = acc[i][j][r];
        else ((unsigned short*)Cv)[(size_t)(row + r)*N + col] = f2bf(acc[i][j][r]);
      }
    }
  }
}

// ---------------------------------------------------------------- RoPE + pack K + transpose V
// qkv rows: bf16 [B*S][NH*128]; cos/sin: f32 [S][128]. Kb: [B][S][128]; Vt: [B][128][S].
__global__ __launch_bounds__(256) void rope_pack(unsigned short* __restrict__ qkv,
                                                 const float* __restrict__ cosb,
                                                 const float* __restrict__ sinb,
                                                 unsigned short* __restrict__ Kb,
                                                 unsigned short* __restrict__ Vt){
  const int bs = blockIdx.x;
  const int s = bs & (SEQ-1), b = bs >> 11;
  const int t = threadIdx.x;
  unsigned short* row = qkv + (size_t)bs * NQKV;
  const float* cr = cosb + (size_t)s * 128;
  const float* sr = sinb + (size_t)s * 128;
  const int h = t >> 4, d0 = (t & 15) * 4;
  unsigned short* q = row + h * 128;
#pragma unroll
  for (int i = 0; i < 4; ++i){
    int d = d0 + i;
    float c  = cr[d], sn = sr[d];
    float x1 = bf2f(q[d]),  x2 = bf2f(q[d + 64]);
    q[d]      = f2bf((x1*c - x2*sn) * QK_SCALE);
    q[d + 64] = f2bf((x2*c + x1*sn) * QK_SCALE);
  }
  if (t < 64){
    const unsigned short* kk = row + H_Q*128;
    int d = t;
    float c  = cr[d], sn = sr[d];
    float x1 = bf2f(kk[d]), x2 = bf2f(kk[d + 64]);
    unsigned short* ko = Kb + ((size_t)b*SEQ + s)*128;
    ko[d]      = f2bf(x1*c - x2*sn);
    ko[d + 64] = f2bf(x2*c + x1*sn);
  }
  if (t < 128){
    Vt[((size_t)b*128 + t)*SEQ + s] = row[(H_Q + 1)*128 + t];
  }
}

// ---------------------------------------------------------------- attention
// Swapped QK^T: S^T tile = mfma(K_frag, Q_frag). LDS-free: P redistributed by shfl.
__global__ __launch_bounds__(256, 2) void attn_fwd(const unsigned short* __restrict__ qkv,
                                                   const unsigned short* __restrict__ Kb,
                                                   const unsigned short* __restrict__ Vt,
                                                   unsigned short* __restrict__ Ob){
  const int tid = threadIdx.x, lane = tid & 63;
  const int g = lane >> 4, m = lane & 15;
  const int b = blockIdx.y >> 4, h = blockIdx.y & 15;
  const int q0 = blockIdx.x * 64 + (tid >> 6) * 16;

  const unsigned short* qrow = qkv + ((size_t)((b << 11) + q0 + m)*NH + h)*128;
  bf16x8 qf[4];
#pragma unroll
  for (int dc = 0; dc < 4; ++dc) qf[dc] = *(const bf16x8*)(qrow + dc*32 + g*8);

  const unsigned short* Kbase = Kb + (size_t)b*SEQ*128;
  const unsigned short* Vbase = Vt + (size_t)b*128*SEQ;
  f32x4 o[8] = {};
  float m_run = -30000.f, s_run = 0.f;

  for (int n0 = 0; n0 < SEQ; n0 += 32){
    f32x4 sc0 = {0.f,0.f,0.f,0.f}, sc1 = {0.f,0.f,0.f,0.f};
    const unsigned short* k0 = Kbase + (size_t)(n0 + m)*128 + g*8;
#pragma unroll
    for (int dc = 0; dc < 4; ++dc){
      bf16x8 kf = *(const bf16x8*)(k0 + dc*32);
      sc0 = __builtin_amdgcn_mfma_f32_16x16x32_bf16(kf, qf[dc], sc0, 0, 0, 0);
    }
    const unsigned short* k1 = k0 + 16*128;
#pragma unroll
    for (int dc = 0; dc < 4; ++dc){
      bf16x8 kf = *(const bf16x8*)(k1 + dc*32);
      sc1 = __builtin_amdgcn_mfma_f32_16x16x32_bf16(kf, qf[dc], sc1, 0, 0, 0);
    }
    // lane (m,g): sc0[r] = S[key n0+4g+r][query m], sc1[r] = S[key n0+16+4g+r][query m]
    float mx = fmaxf(fmaxf(fmaxf(sc0[0],sc0[1]), fmaxf(sc0[2],sc0[3])),
                     fmaxf(fmaxf(sc1[0],sc1[1]), fmaxf(sc1[2],sc1[3])));
    mx = fmaxf(mx, __shfl_xor(mx, 16));
    mx = fmaxf(mx, __shfl_xor(mx, 32));
    float mn  = fmaxf(m_run, mx);
    float rsc = __expf(m_run - mn);
    m_run = mn;
    float p0[4], p1[4], psum = 0.f;
#pragma unroll
    for (int r = 0; r < 4; ++r){
      p0[r] = __expf(sc0[r] - mn);
      p1[r] = __expf(sc1[r] - mn);
      psum += p0[r] + p1[r];
    }
    psum += __shfl_xor(psum, 16);
    psum += __shfl_xor(psum, 32);
    s_run = s_run * rsc + psum;

    // Redistribute P into PV A-fragment: lane (m,g) needs keys 8g..8g+7,
    // held by lanes (m, 2*(g&1)) and (m, 2*(g&1)+1): p0 if g<2 else p1.
    unsigned int P01 = (unsigned)f2bf(p0[0]) | ((unsigned)f2bf(p0[1]) << 16);
    unsigned int P23 = (unsigned)f2bf(p0[2]) | ((unsigned)f2bf(p0[3]) << 16);
    unsigned int Q01 = (unsigned)f2bf(p1[0]) | ((unsigned)f2bf(p1[1]) << 16);
    unsigned int Q23 = (unsigned)f2bf(p1[2]) | ((unsigned)f2bf(p1[3]) << 16);
    int s0 = m + ((g & 1) << 5), s1 = s0 + 16;
    int aP0 = __shfl((int)P01, s0), aP1 = __shfl((int)P23, s0);
    int aP2 = __shfl((int)P01, s1), aP3 = __shfl((int)P23, s1);
    int aQ0 = __shfl((int)Q01, s0), aQ1 = __shfl((int)Q23, s0);
    int aQ2 = __shfl((int)Q01, s1), aQ3 = __shfl((int)Q23, s1);
    union { int w[4]; bf16x8 v; } U;
    U.w[0] = (g < 2) ? aP0 : aQ0;
    U.w[1] = (g < 2) ? aP1 : aQ1;
    U.w[2] = (g < 2) ? aP2 : aQ2;
    U.w[3] = (g < 2) ? aP3 : aQ3;
    bf16x8 pf = U.v;

    float rr[4];
#pragma unroll
    for (int r = 0; r < 4; ++r) rr[r] = __shfl(rsc, g*4 + r);
#pragma unroll
    for (int dt = 0; dt < 8; ++dt){
#pragma unroll
      for (int r = 0; r < 4; ++r) o[dt][r] *= rr[r];
      bf16x8 vf = *(const bf16x8*)(Vbase + (size_t)(dt*16 + m)*SEQ + n0 + g*8);
      o[dt] = __builtin_amdgcn_mfma_f32_16x16x32_bf16(pf, vf, o[dt], 0, 0, 0);
    }
  }

  float inv = 1.f / s_run;
  float iv[4];
#pragma unroll
  for (int r = 0; r < 4; ++r) iv[r] = __shfl(inv, g*4 + r);
  unsigned short* orow = Ob + (size_t)((b << 11) + q0)*HID + h*128;
#pragma unroll
  for (int dt = 0; dt < 8; ++dt)
#pragma unroll
    for (int r = 0; r < 4; ++r)
      orow[(size_t)(g*4 + r)*HID + dt*16 + m] = f2bf(o[dt][r] * iv[r]);
}

// ---------------------------------------------------------------- launch
extern "C" void kernel_launch(void* const* d_in, const int* in_sizes, int n_in,
                              void* d_out, int out_size, void* d_ws, size_t ws_size,
                              hipStream_t stream){
  const float* hidden = (const float*)d_in[0];   // f32 per reference setup_inputs
  const float* cosb   = (const float*)d_in[1];
  const float* sinb   = (const float*)d_in[2];
  const float* wqkv   = (const float*)d_in[3];
  const float* wo     = (const float*)d_in[4];
  float* out = (float*)d_out;                    // f32 output (reference returns float32)

  // workspace (47.2 MB with aliasing):
  char* ws = (char*)d_ws;
  unsigned short* qkvb  = (unsigned short*)ws; ws += (size_t)BATCH*SEQ*NQKV*2;  // 18.9 MB
  unsigned short* hidb  = (unsigned short*)ws; ws += (size_t)BATCH*SEQ*HID*2;   // 16.8 MB (gemm1 A)
  unsigned short* attnb = hidb;                                                 // alias: dead after gemm1
  unsigned short* Kbf   = (unsigned short*)ws; ws += (size_t)BATCH*SEQ*128*2;   // 1.05 MB
  unsigned short* Vt    = (unsigned short*)ws; ws += (size_t)BATCH*SEQ*128*2;   // 1.05 MB
  unsigned short* wqkvT = (unsigned short*)ws; ws += (size_t)NQKV*HID*2;        // 9.44 MB
  unsigned short* woT   = wqkvT;                                                // alias: dead after gemm1

  convert_bf16<<<dim3(BATCH*SEQ*HID/4096), 256, 0, stream>>>(hidden, hidb);
  transpose_f2b<<<dim3(NQKV/64, HID/64), 256, 0, stream>>>(wqkv, wqkvT, HID, NQKV);
  gemm_bt<false><<<dim3(BATCH*SEQ/128, NQKV/128), 256, 0, stream>>>(hidb, wqkvT, qkvb,
                                                                    BATCH*SEQ, NQKV, HID);
  rope_pack<<<dim3(BATCH*SEQ), 256, 0, stream>>>(qkvb, cosb, sinb, Kbf, Vt);
  transpose_f2b<<<dim3(HID/64, HID/64), 256, 0, stream>>>(wo, woT, HID, HID);
  attn_fwd<<<dim3(SEQ/64, BATCH*H_Q), 256, 0, stream>>>(qkvb, Kbf, Vt, attnb);
  gemm_bt<true><<<dim3(BATCH*SEQ/128, HID/128), 256, 0, stream>>>(attnb, woT, out,
                                                                  BATCH*SEQ, HID, HID);
}

// Round 8
// 567.201 us; speedup vs baseline: 1.0012x; 1.0012x over previous
//
#include <hip/hip_runtime.h>

typedef __attribute__((ext_vector_type(8))) short bf16x8;
typedef __attribute__((ext_vector_type(4))) float f32x4;
typedef __attribute__((ext_vector_type(8))) unsigned short u16x8;

#define H_Q   16
#define NH    18            // 16 q heads + 1 k + 1 v
#define SEQ   2048
#define BATCH 2
#define HID   2048
#define NQKV  2304          // NH*128
#define QK_SCALE 0.08838834764831845f  // 1/sqrt(128)

__device__ __forceinline__ float bf2f(unsigned short u){
  union { unsigned int u; float f; } x; x.u = ((unsigned int)u) << 16; return x.f;
}
__device__ __forceinline__ unsigned short f2bf(float f){
  union { float f; unsigned int u; } x; x.f = f;
  unsigned int r = x.u + 0x7fffu + ((x.u >> 16) & 1u);
  return (unsigned short)(r >> 16);
}

// ---------------------------------------------------------------- f32 -> bf16 convert
__global__ __launch_bounds__(256) void convert_bf16(const float* __restrict__ src,
                                                    unsigned short* __restrict__ dst){
  const size_t i0 = ((size_t)blockIdx.x * 256 + threadIdx.x) * 16;
  f32x4 a = *(const f32x4*)(src + i0);
  f32x4 b = *(const f32x4*)(src + i0 + 4);
  f32x4 c = *(const f32x4*)(src + i0 + 8);
  f32x4 d = *(const f32x4*)(src + i0 + 12);
  u16x8 lo, hi;
#pragma unroll
  for (int j = 0; j < 4; ++j){
    lo[j] = f2bf(a[j]); lo[4+j] = f2bf(b[j]);
    hi[j] = f2bf(c[j]); hi[4+j] = f2bf(d[j]);
  }
  *(u16x8*)(dst + i0)     = lo;
  *(u16x8*)(dst + i0 + 8) = hi;
}

// ---------------------------------------------------------------- transpose + convert
// W: K x N (row-major, f32) -> WT: N x K (row-major, bf16). 64x64 tiles.
__global__ __launch_bounds__(256) void transpose_f2b(const float* __restrict__ W,
                                                     unsigned short* __restrict__ WT,
                                                     int K, int N){
  __shared__ float tile[64][72];
  const int t = threadIdx.x;
  const int nt = blockIdx.x * 64, kt = blockIdx.y * 64;
#pragma unroll
  for (int p = 0; p < 2; ++p){
    int slot = p*256 + t, r = slot >> 3, c = (slot & 7) * 8;
    *(f32x4*)&tile[r][c]     = *(const f32x4*)(W + (size_t)(kt + r)*N + nt + c);
    *(f32x4*)&tile[r][c + 4] = *(const f32x4*)(W + (size_t)(kt + r)*N + nt + c + 4);
  }
  __syncthreads();
#pragma unroll
  for (int p = 0; p < 2; ++p){
    int slot = p*256 + t, r = slot >> 3, c = (slot & 7) * 8;
    u16x8 v;
#pragma unroll
    for (int j = 0; j < 8; ++j) v[j] = f2bf(tile[c + j][r]);
    *(u16x8*)(WT + (size_t)(nt + r)*K + kt + c) = v;
  }
}

// ---------------------------------------------------------------- GEMM (B^T input)
// C(MxN) = A(MxK, rm) * Bt(NxK, rm)^T.  128x128 tile, BK=32, 4 waves (2x2 of 64x64).
template<bool F32OUT>
__global__ __launch_bounds__(256, 2) void gemm_bt(const unsigned short* __restrict__ A,
                                                  const unsigned short* __restrict__ Bt,
                                                  void* __restrict__ Cv,
                                                  int M, int N, int K){
  __shared__ unsigned short lds[2][2][128*32];
  const int tid  = threadIdx.x;
  const int wave = tid >> 6, lane = tid & 63;
  const int row0 = blockIdx.x * 128, col0 = blockIdx.y * 128;
  const int wr = (wave >> 1) * 64, wc = (wave & 1) * 64;
  const int lm = lane & 15, lk = (lane >> 4) * 8;
  f32x4 acc[4][4] = {};

  auto stage = [&](int buf, int kt){
#pragma unroll
    for (int i = 0; i < 2; ++i){
      int slot = i*256 + tid;
      int r = slot >> 2, kc = (slot & 3) * 8;
      const unsigned short* ga = A  + (size_t)(row0 + r)*K + kt*32 + kc;
      const unsigned short* gb = Bt + (size_t)(col0 + r)*K + kt*32 + kc;
      unsigned short* la = &lds[buf][0][(i*256 + (wave << 6)) * 8];
      unsigned short* lb = &lds[buf][1][(i*256 + (wave << 6)) * 8];
      __builtin_amdgcn_global_load_lds((const __attribute__((address_space(1))) void*)ga,
                                       (__attribute__((address_space(3))) void*)la, 16, 0, 0);
      __builtin_amdgcn_global_load_lds((const __attribute__((address_space(1))) void*)gb,
                                       (__attribute__((address_space(3))) void*)lb, 16, 0, 0);
    }
  };

  stage(0, 0);
  const int KT = K >> 5;
  int buf = 0;
  for (int kt = 0; kt < KT; ++kt){
    __syncthreads();                       // drains vmcnt: staged tile ready, prev reads done
    if (kt + 1 < KT) stage(buf ^ 1, kt + 1);
    const unsigned short* la = lds[buf][0];
    const unsigned short* lb = lds[buf][1];
    bf16x8 af[4], bfr[4];
#pragma unroll
    for (int i = 0; i < 4; ++i) af[i]  = *(const bf16x8*)&la[(wr + i*16 + lm)*32 + lk];
#pragma unroll
    for (int j = 0; j < 4; ++j) bfr[j] = *(const bf16x8*)&lb[(wc + j*16 + lm)*32 + lk];
#pragma unroll
    for (int i = 0; i < 4; ++i)
#pragma unroll
      for (int j = 0; j < 4; ++j)
        acc[i][j] = __builtin_amdgcn_mfma_f32_16x16x32_bf16(af[i], bfr[j], acc[i][j], 0, 0, 0);
    buf ^= 1;
  }

#pragma unroll
  for (int i = 0; i < 4; ++i){
    int row = row0 + wr + i*16 + (lane >> 4) * 4;
#pragma unroll
    for (int j = 0; j < 4; ++j){
      int col = col0 + wc + j*16 + lm;
#pragma unroll
      for (int r = 0; r < 4; ++r){
        if (F32OUT) ((float*)Cv)[(size_t)(row + r)*N + col] = acc[i][j][r];
        else ((unsigned short*)Cv)[(size_t)(row + r)*N + col] = f2bf(acc[i][j][r]);
      }
    }
  }
}

// ---------------------------------------------------------------- RoPE + pack K + transpose V
__global__ __launch_bounds__(256) void rope_pack(unsigned short* __restrict__ qkv,
                                                 const float* __restrict__ cosb,
                                                 const float* __restrict__ sinb,
                                                 unsigned short* __restrict__ Kb,
                                                 unsigned short* __restrict__ Vt){
  const int bs = blockIdx.x;
  const int s = bs & (SEQ-1), b = bs >> 11;
  const int t = threadIdx.x;
  unsigned short* row = qkv + (size_t)bs * NQKV;
  const float* cr = cosb + (size_t)s * 128;
  const float* sr = sinb + (size_t)s * 128;
  const int h = t >> 4, d0 = (t & 15) * 4;
  unsigned short* q = row + h * 128;
#pragma unroll
  for (int i = 0; i < 4; ++i){
    int d = d0 + i;
    float c  = cr[d], sn = sr[d];
    float x1 = bf2f(q[d]),  x2 = bf2f(q[d + 64]);
    q[d]      = f2bf((x1*c - x2*sn) * QK_SCALE);
    q[d + 64] = f2bf((x2*c + x1*sn) * QK_SCALE);
  }
  if (t < 64){
    const unsigned short* kk = row + H_Q*128;
    int d = t;
    float c  = cr[d], sn = sr[d];
    float x1 = bf2f(kk[d]), x2 = bf2f(kk[d + 64]);
    unsigned short* ko = Kb + ((size_t)b*SEQ + s)*128;
    ko[d]      = f2bf(x1*c - x2*sn);
    ko[d + 64] = f2bf(x2*c + x1*sn);
  }
  if (t < 128){
    Vt[((size_t)b*128 + t)*SEQ + s] = row[(H_Q + 1)*128 + t];
  }
}

// ---------------------------------------------------------------- attention
// Swapped QK^T, LDS-free shfl P-redistribution, software-pipelined K/V:
//   K(t+1) issued after QK(t) consumes kf; V(t) issued before softmax(t);
//   PV waits vmcnt<=8 (K prefetch stays in flight). Skip-rescale when max unchanged.
__global__ __launch_bounds__(256, 2) void attn_fwd(const unsigned short* __restrict__ qkv,
                                                   const unsigned short* __restrict__ Kb,
                                                   const unsigned short* __restrict__ Vt,
                                                   unsigned short* __restrict__ Ob){
  const int tid = threadIdx.x, lane = tid & 63;
  const int g = lane >> 4, m = lane & 15;
  const int wg = blockIdx.x;               // 1024 linear blocks
  const int bh = wg & 31, qb = wg >> 5;
  const int b = bh >> 4, h = bh & 15;
  const int q0 = qb * 64 + (tid >> 6) * 16;

  const unsigned short* qrow = qkv + ((size_t)((b << 11) + q0 + m)*NH + h)*128;
  bf16x8 qf[4];
#pragma unroll
  for (int dc = 0; dc < 4; ++dc) qf[dc] = *(const bf16x8*)(qrow + dc*32 + g*8);

  const unsigned short* Kbase = Kb + (size_t)b*SEQ*128;
  const unsigned short* Vbase = Vt + (size_t)b*128*SEQ;

  // preload K(0) fragments
  bf16x8 kf0[4], kf1[4];
  {
    const unsigned short* k0 = Kbase + (size_t)m*128 + g*8;
#pragma unroll
    for (int dc = 0; dc < 4; ++dc) kf0[dc] = *(const bf16x8*)(k0 + dc*32);
#pragma unroll
    for (int dc = 0; dc < 4; ++dc) kf1[dc] = *(const bf16x8*)(k0 + 16*128 + dc*32);
  }

  f32x4 o[8] = {};
  float m_run = -30000.f, s_run = 0.f;

  for (int n0 = 0; n0 < SEQ; n0 += 32){
    // ---- QK^T on prefetched K
    f32x4 sc0 = {0.f,0.f,0.f,0.f}, sc1 = {0.f,0.f,0.f,0.f};
    __builtin_amdgcn_s_setprio(1);
#pragma unroll
    for (int dc = 0; dc < 4; ++dc)
      sc0 = __builtin_amdgcn_mfma_f32_16x16x32_bf16(kf0[dc], qf[dc], sc0, 0, 0, 0);
#pragma unroll
    for (int dc = 0; dc < 4; ++dc)
      sc1 = __builtin_amdgcn_mfma_f32_16x16x32_bf16(kf1[dc], qf[dc], sc1, 0, 0, 0);
    __builtin_amdgcn_s_setprio(0);

    // ---- issue V(t) loads (latency hides under softmax)
    bf16x8 vf[8];
#pragma unroll
    for (int dt = 0; dt < 8; ++dt)
      vf[dt] = *(const bf16x8*)(Vbase + (size_t)(dt*16 + m)*SEQ + n0 + g*8);

    // ---- prefetch K(t+1) (latency hides under softmax+PV; issued last so
    //      PV's V-wait leaves these in flight)
    if (n0 + 32 < SEQ){
      const unsigned short* kn = Kbase + (size_t)(n0 + 32 + m)*128 + g*8;
#pragma unroll
      for (int dc = 0; dc < 4; ++dc) kf0[dc] = *(const bf16x8*)(kn + dc*32);
#pragma unroll
      for (int dc = 0; dc < 4; ++dc) kf1[dc] = *(const bf16x8*)(kn + 16*128 + dc*32);
    }

    // ---- online softmax (per query m; lanes {m,m+16,m+32,m+48} hold its keys)
    float mx = fmaxf(fmaxf(fmaxf(sc0[0],sc0[1]), fmaxf(sc0[2],sc0[3])),
                     fmaxf(fmaxf(sc1[0],sc1[1]), fmaxf(sc1[2],sc1[3])));
    mx = fmaxf(mx, __shfl_xor(mx, 16));
    mx = fmaxf(mx, __shfl_xor(mx, 32));
    const bool grew = __any(mx > m_run);
    float mn, rsc;
    if (grew){ mn = fmaxf(m_run, mx); rsc = __expf(m_run - mn); m_run = mn; }
    else     { mn = m_run;            rsc = 1.f; }
    float p0[4], p1[4], psum = 0.f;
#pragma unroll
    for (int r = 0; r < 4; ++r){
      p0[r] = __expf(sc0[r] - mn);
      p1[r] = __expf(sc1[r] - mn);
      psum += p0[r] + p1[r];
    }
    psum += __shfl_xor(psum, 16);
    psum += __shfl_xor(psum, 32);
    s_run = s_run * rsc + psum;

    // ---- redistribute P into PV A-fragment (8 shfl + 4 selects)
    unsigned int P01 = (unsigned)f2bf(p0[0]) | ((unsigned)f2bf(p0[1]) << 16);
    unsigned int P23 = (unsigned)f2bf(p0[2]) | ((unsigned)f2bf(p0[3]) << 16);
    unsigned int Q01 = (unsigned)f2bf(p1[0]) | ((unsigned)f2bf(p1[1]) << 16);
    unsigned int Q23 = (unsigned)f2bf(p1[2]) | ((unsigned)f2bf(p1[3]) << 16);
    int s0 = m + ((g & 1) << 5), s1 = s0 + 16;
    int aP0 = __shfl((int)P01, s0), aP1 = __shfl((int)P23, s0);
    int aP2 = __shfl((int)P01, s1), aP3 = __shfl((int)P23, s1);
    int aQ0 = __shfl((int)Q01, s0), aQ1 = __shfl((int)Q23, s0);
    int aQ2 = __shfl((int)Q01, s1), aQ3 = __shfl((int)Q23, s1);
    union { int w[4]; bf16x8 v; } U;
    U.w[0] = (g < 2) ? aP0 : aQ0;
    U.w[1] = (g < 2) ? aP1 : aQ1;
    U.w[2] = (g < 2) ? aP2 : aQ2;
    U.w[3] = (g < 2) ? aP3 : aQ3;
    bf16x8 pf = U.v;

    // ---- rescale O only when max grew (exact: rsc==1 otherwise)
    if (grew){
      float rr[4];
#pragma unroll
      for (int r = 0; r < 4; ++r) rr[r] = __shfl(rsc, g*4 + r);
#pragma unroll
      for (int dt = 0; dt < 8; ++dt)
#pragma unroll
        for (int r = 0; r < 4; ++r) o[dt][r] *= rr[r];
    }

    // ---- PV
    __builtin_amdgcn_s_setprio(1);
#pragma unroll
    for (int dt = 0; dt < 8; ++dt)
      o[dt] = __builtin_amdgcn_mfma_f32_16x16x32_bf16(pf, vf[dt], o[dt], 0, 0, 0);
    __builtin_amdgcn_s_setprio(0);
  }

  float inv = 1.f / s_run;
  float iv[4];
#pragma unroll
  for (int r = 0; r < 4; ++r) iv[r] = __shfl(inv, g*4 + r);
  unsigned short* orow = Ob + (size_t)((b << 11) + q0)*HID + h*128;
#pragma unroll
  for (int dt = 0; dt < 8; ++dt)
#pragma unroll
    for (int r = 0; r < 4; ++r)
      orow[(size_t)(g*4 + r)*HID + dt*16 + m] = f2bf(o[dt][r] * iv[r]);
}

// ---------------------------------------------------------------- launch
extern "C" void kernel_launch(void* const* d_in, const int* in_sizes, int n_in,
                              void* d_out, int out_size, void* d_ws, size_t ws_size,
                              hipStream_t stream){
  const float* hidden = (const float*)d_in[0];
  const float* cosb   = (const float*)d_in[1];
  const float* sinb   = (const float*)d_in[2];
  const float* wqkv   = (const float*)d_in[3];
  const float* wo     = (const float*)d_in[4];
  float* out = (float*)d_out;                    // f32 output

  char* ws = (char*)d_ws;
  unsigned short* qkvb  = (unsigned short*)ws; ws += (size_t)BATCH*SEQ*NQKV*2;  // 18.9 MB
  unsigned short* hidb  = (unsigned short*)ws; ws += (size_t)BATCH*SEQ*HID*2;   // 16.8 MB
  unsigned short* attnb = hidb;                                                 // alias: dead after gemm1
  unsigned short* Kbf   = (unsigned short*)ws; ws += (size_t)BATCH*SEQ*128*2;   // 1.05 MB
  unsigned short* Vt    = (unsigned short*)ws; ws += (size_t)BATCH*SEQ*128*2;   // 1.05 MB
  unsigned short* wqkvT = (unsigned short*)ws; ws += (size_t)NQKV*HID*2;        // 9.44 MB
  unsigned short* woT   = wqkvT;                                                // alias: dead after gemm1

  convert_bf16<<<dim3(BATCH*SEQ*HID/4096), 256, 0, stream>>>(hidden, hidb);
  transpose_f2b<<<dim3(NQKV/64, HID/64), 256, 0, stream>>>(wqkv, wqkvT, HID, NQKV);
  gemm_bt<false><<<dim3(BATCH*SEQ/128, NQKV/128), 256, 0, stream>>>(hidb, wqkvT, qkvb,
                                                                    BATCH*SEQ, NQKV, HID);
  rope_pack<<<dim3(BATCH*SEQ), 256, 0, stream>>>(qkvb, cosb, sinb, Kbf, Vt);
  transpose_f2b<<<dim3(HID/64, HID/64), 256, 0, stream>>>(wo, woT, HID, HID);
  attn_fwd<<<dim3(SEQ/64 * BATCH*H_Q), 256, 0, stream>>>(qkvb, Kbf, Vt, attnb);
  gemm_bt<true><<<dim3(BATCH*SEQ/128, HID/128), 256, 0, stream>>>(attnb, woT, out,
                                                                  BATCH*SEQ, HID, HID);
}